// Round 10
// baseline (268.321 us; speedup 1.0000x reference)
//
#include <hip/hip_runtime.h>
#include <cstdint>

#define DIM   1024
#define NH    16
#define HD    64
#define SEQ   2048
#define BATCH 4
// 0.125 * log2(e): fold qk scale into exp2 (applied to Q in gemm_bt256 epilogue)
#define QK_EXP2_SCALE 0.18033688011112042f

typedef _Float16 half8  __attribute__((ext_vector_type(8)));
typedef __fp16   fp16x2 __attribute__((ext_vector_type(2)));
typedef float    f32x4  __attribute__((ext_vector_type(4)));

#define GLOBAL_AS __attribute__((address_space(1)))
#define LDS_AS    __attribute__((address_space(3)))

__device__ __forceinline__ ushort f2h(float f) {
  union { _Float16 h; ushort u; } c; c.h = (_Float16)f; return c.u;  // RNE
}
// async global->LDS, 16B/lane; LDS dest is wave-uniform base + lane*16
__device__ __forceinline__ void async_cp16(const ushort* g, ushort* l) {
  __builtin_amdgcn_global_load_lds((const GLOBAL_AS uint32_t*)g,
                                   (LDS_AS uint32_t*)l, 16, 0, 0);
}

// fused f32->f16 convert of x, w_qkv, w_proj
__global__ __launch_bounds__(256) void cvt3_f32_to_f16(
    const float4* __restrict__ x, const float4* __restrict__ wq,
    const float4* __restrict__ wp, ushort4* __restrict__ xo,
    ushort4* __restrict__ wqo, ushort4* __restrict__ wpo) {
  int i = blockIdx.x * 256 + threadIdx.x;
  const float4* src; ushort4* dst; int j;
  if (i < 2097152)      { src = x;  dst = xo;  j = i; }
  else if (i < 2883584) { src = wq; dst = wqo; j = i - 2097152; }
  else                  { src = wp; dst = wpo; j = i - 2883584; }
  float4 v = src[j];
  dst[j] = make_ushort4(f2h(v.x), f2h(v.y), f2h(v.z), f2h(v.w));
}

// C = A(MxK) * Bt(NxK)^T, f16 in, fp32 accum. 128x256 tile, BK=64 --
// MEASURED BEST of the 4-wave family (R8 ledger: ~60-80us, <=84.9 cutoff).
// R7's 128x384 regressed (86us): 320 regs/wave -> 1 block/CU. acc[4][8]=128
// AGPR fits the 240/wave budget. launch_bounds(256,2): (256,3) collapses.
// T2 LDS swizzle (verified R3: conflicts 1.4e7 -> ~0, -12us).
// Epilogue: Q cols (<DIM) pre-scaled by QK_EXP2_SCALE for attn exp2.
// FROZEN since R8.
__global__ __launch_bounds__(256, 2) void gemm_bt256(
    const ushort* __restrict__ A, const ushort* __restrict__ Bt,
    ushort* __restrict__ Ch, int M, int N, int K) {
  __shared__ ushort As[128 * 64];
  __shared__ ushort Bs[256 * 64];
  const int t    = threadIdx.x;
  const int w    = t >> 6;
  const int lane = t & 63;
  const int quad = lane >> 4;
  const int l16  = lane & 15;
  const int wm   = w >> 1, wn = w & 1;

  // supertile swizzle (8 m-blocks x full n-strip)
  const int num_n = N >> 8;
  const int SUPER = 8;
  const int bid   = blockIdx.x;
  const int strip = bid / (SUPER * num_n);
  const int rem   = bid % (SUPER * num_n);
  const int m0 = (strip * SUPER + (rem % SUPER)) * 128;
  const int n0 = (rem / SUPER) * 256;

  f32x4 acc[4][8];
  #pragma unroll
  for (int it = 0; it < 4; ++it)
    #pragma unroll
    for (int jt = 0; jt < 8; ++jt) acc[it][jt] = (f32x4){0, 0, 0, 0};

  const int srow = lane >> 3;                          // 0..7 within 8-row group
  const int scol = ((lane & 7) ^ (lane >> 3)) * 8;     // swizzled source chunk
  const int cxa  = l16 & 7;                            // read-side row&7

  for (int k0 = 0; k0 < K; k0 += 64) {
    __syncthreads();   // prev-tile frag reads done
    #pragma unroll
    for (int p = 0; p < 4; ++p) {    // A: wave w stages rows w*32..w*32+31
      const int rbase = w * 32 + p * 8;
      async_cp16(&A[(size_t)(m0 + rbase + srow) * K + k0 + scol], &As[rbase * 64]);
    }
    #pragma unroll
    for (int p = 0; p < 8; ++p) {    // B: wave w stages rows w*64..w*64+63
      const int rbase = w * 64 + p * 8;
      async_cp16(&Bt[(size_t)(n0 + rbase + srow) * K + k0 + scol], &Bs[rbase * 64]);
    }
    __syncthreads();   // staging drained
    #pragma unroll
    for (int kk = 0; kk < 2; ++kk) {
      const int ko = ((kk * 4 + quad) ^ cxa) * 8;   // swizzled read chunk
      half8 a[4];
      #pragma unroll
      for (int it = 0; it < 4; ++it)
        a[it] = *(const half8*)&As[(wm * 64 + it * 16 + l16) * 64 + ko];
      #pragma unroll
      for (int jt = 0; jt < 8; ++jt) {
        half8 b = *(const half8*)&Bs[(wn * 128 + jt * 16 + l16) * 64 + ko];
        #pragma unroll
        for (int it = 0; it < 4; ++it)
          acc[it][jt] = __builtin_amdgcn_mfma_f32_16x16x32_f16(a[it], b, acc[it][jt], 0, 0, 0);
      }
    }
  }

  #pragma unroll
  for (int it = 0; it < 4; ++it)
    #pragma unroll
    for (int jt = 0; jt < 8; ++jt) {
      const int colbase = n0 + wn * 128 + jt * 16;
      const float qs = (colbase < DIM) ? QK_EXP2_SCALE : 1.0f;
      #pragma unroll
      for (int i = 0; i < 4; ++i) {
        int row = m0 + wm * 64 + it * 16 + quad * 4 + i;   // C/D row=quad*4+reg
        int col = n0 + wn * 128 + jt * 16 + l16;           // C/D col=lane&15
        Ch[(size_t)row * N + col] = f2h(acc[it][jt][i] * qs);
      }
    }
}

// proj GEMM v10: 64x128 tile, 1024 blocks. LEDGER DIAGNOSIS (R2/R7 both
// had measured bt256, so bt128+gaps ≈ 100us both times = ~180 TF -- the
// worst kernel in the pipeline). R9 proved it's NOT a register problem
// ((256,2) changed nothing). Structural cause: 512 blocks = 2 blocks/CU =
// 2 waves/SIMD, 32 MFMA/wave between barriers -- no TLP to cover the
// staging drain. 64x128 -> 1024 blocks = 4 blocks/CU (LDS 24KB x4 = 96 <=
// 160; regs ~110/wave x4 = 440 <= 512/SIMD): 4 independent blocks overlap
// each other's barrier drains (the mechanism that makes bt256 work).
// (256,3): budget 170 >= ~110 need (safe, unlike R2's 218>170) and guards
// the plain-bounds trap (24KB LDS -> 6-wave target -> ~85-reg budget <
// need -> spill, the R4/R5 mechanism). Wave-tile 32x64, acc[2][4]=32 AGPR.
// Same T2 swizzle + fused bias.
__global__ __launch_bounds__(256, 3) void gemm_bt128(
    const ushort* __restrict__ A, const ushort* __restrict__ Bt,
    float* __restrict__ Cf, const float* __restrict__ bias,
    int M, int N, int K) {
  __shared__ ushort As[64 * 64];
  __shared__ ushort Bs[128 * 64];
  const int t    = threadIdx.x;
  const int w    = t >> 6;
  const int lane = t & 63;
  const int quad = lane >> 4;
  const int l16  = lane & 15;
  const int wm   = w >> 1, wn = w & 1;   // 2m x 2n wave grid

  // 128 m-blocks (64 rows) x 8 n-strips (128 cols); supertile 8x8
  const int num_n = N >> 7;                  // 8
  const int SUPER = 8;
  const int bid   = blockIdx.x;
  const int strip = bid / (SUPER * num_n);   // 0..15
  const int rem   = bid % (SUPER * num_n);
  const int m0 = (strip * SUPER + (rem % SUPER)) * 64;
  const int n0 = (rem / SUPER) * 128;

  f32x4 acc[2][4];
  #pragma unroll
  for (int it = 0; it < 2; ++it)
    #pragma unroll
    for (int jt = 0; jt < 4; ++jt) acc[it][jt] = (f32x4){0, 0, 0, 0};

  const int srow = lane >> 3;
  const int scol = ((lane & 7) ^ (lane >> 3)) * 8;
  const int cxa  = l16 & 7;

  for (int k0 = 0; k0 < K; k0 += 64) {
    __syncthreads();
    #pragma unroll
    for (int p = 0; p < 2; ++p) {    // A: wave w stages rows w*16..w*16+15
      const int rbase = w * 16 + p * 8;
      async_cp16(&A[(size_t)(m0 + rbase + srow) * K + k0 + scol], &As[rbase * 64]);
    }
    #pragma unroll
    for (int p = 0; p < 4; ++p) {    // B: wave w stages rows w*32..w*32+31
      const int rbase = w * 32 + p * 8;
      async_cp16(&Bt[(size_t)(n0 + rbase + srow) * K + k0 + scol], &Bs[rbase * 64]);
    }
    __syncthreads();
    #pragma unroll
    for (int kk = 0; kk < 2; ++kk) {
      const int ko = ((kk * 4 + quad) ^ cxa) * 8;
      half8 a[2], b[4];
      #pragma unroll
      for (int it = 0; it < 2; ++it)
        a[it] = *(const half8*)&As[(wm * 32 + it * 16 + l16) * 64 + ko];
      #pragma unroll
      for (int jt = 0; jt < 4; ++jt)
        b[jt] = *(const half8*)&Bs[(wn * 64 + jt * 16 + l16) * 64 + ko];
      #pragma unroll
      for (int it = 0; it < 2; ++it)
        #pragma unroll
        for (int jt = 0; jt < 4; ++jt)
          acc[it][jt] = __builtin_amdgcn_mfma_f32_16x16x32_f16(a[it], b[jt], acc[it][jt], 0, 0, 0);
    }
  }

  #pragma unroll
  for (int it = 0; it < 2; ++it)
    #pragma unroll
    for (int jt = 0; jt < 4; ++jt)
      #pragma unroll
      for (int i = 0; i < 4; ++i) {
        int row = m0 + wm * 32 + it * 16 + quad * 4 + i;
        int col = n0 + wn * 64 + jt * 16 + l16;
        Cf[(size_t)row * N + col] = acc[it][jt][i] + bias[col];
      }
}

// MFMA flash attention -- v2 body (measured best: 84.5us, VGPR 112,
// 2 blocks/CU) + XCD co-location grid (R8 verified: FETCH 139->25.4MB).
// Issue-bound (MfmaUtil 33, VALUBusy 39, BW 4%); five structural rewrites
// (R3-R6) all lost; body FROZEN.
// Transposed-S (S^T = K Q^T; P^T in registers as PV B-operand; V^T staged
// with verified key permutation). NO-max softmax. 64 q/wave, 256 q/block;
// 64-key tiles, K/V double-buffered, 1 barrier/tile. Conditional next-tile
// prefetch (compiler sinks it to the LDS-write point -- measured fine).
// QK scale pre-folded into Q by gemm_bt256, so P = exp2(st) directly.
__global__ __launch_bounds__(256, 2) void attn_mfma(
    const ushort* __restrict__ qkv, ushort* __restrict__ attn_out) {
  constexpr int LDT = 68;
  __shared__ ushort Qs[256 * LDT];
  __shared__ ushort Ks[2][64 * LDT];
  __shared__ ushort Vt[2][64 * LDT];   // [d][permuted key]

  const int t    = threadIdx.x;
  const int w    = t >> 6;
  const int lane = t & 63;
  const int quad = lane >> 4;
  const int l16  = lane & 15;

  // XCD co-location: blocks of one (h,b) have ids {hb + 64*qc} == hb (mod 8)
  const int id = blockIdx.x;
  const int hb = id & 63;
  const int q0 = (id >> 6) * 256;
  const int h  = hb & 15;
  const int b  = hb >> 4;

  const int srow = t >> 2;   // K staging row 0..63
  const int sseg = t & 3;    // 16-elem segment
  const int vp   = t & 31;   // V key-pair index m: keys (2m, 2m+1)
  const int vs   = t >> 5;   // V d-segment of 8
  const int vpos = ((vp >> 4) << 5) + (((vp >> 1) & 3) << 3)
                 + (((vp >> 3) & 1) << 2) + ((vp & 1) << 1);

  // ---- stage Q: 256 rows x 64 d (2 passes) ----
  #pragma unroll
  for (int pass = 0; pass < 2; ++pass) {
    const int qrow = pass * 128 + (t >> 1), qseg = t & 1;
    const ushort* qp = qkv + (size_t)(b * SEQ + q0 + qrow) * (3 * DIM)
                       + h * HD + qseg * 32;
    #pragma unroll
    for (int e = 0; e < 4; ++e)
      *(int4*)&Qs[qrow * LDT + qseg * 32 + e * 8] = *(const int4*)(qp + e * 8);
  }

  f32x4 ot[4][4];   // O^T: ot[qt][nt][i] = O[q=w*64+qt*16+l16][d=nt*16+quad*4+i]
  float lacc[4] = {0.0f, 0.0f, 0.0f, 0.0f};
  #pragma unroll
  for (int qt = 0; qt < 4; ++qt)
    #pragma unroll
    for (int nt = 0; nt < 4; ++nt) ot[qt][nt] = (f32x4){0, 0, 0, 0};

  // per-thread K/V tile base pointers (tile step = 64 rows of qkv)
  const ushort* kbase = qkv + (size_t)(b * SEQ + srow) * (3 * DIM)
                        + DIM + h * HD + sseg * 16;
  const ushort* vbase = qkv + (size_t)(b * SEQ + 2 * vp) * (3 * DIM)
                        + 2 * DIM + h * HD + vs * 8;
  const size_t tstep = (size_t)64 * (3 * DIM);

  // ---- prefetch + stage tile 0 ----
  int4 kr0 = *(const int4*)(kbase + 0);
  int4 kr1 = *(const int4*)(kbase + 8);
  int4 vr0 = *(const int4*)(vbase);
  int4 vr1 = *(const int4*)(vbase + 3 * DIM);
  {
    *(int4*)&Ks[0][srow * LDT + sseg * 16 + 0] = kr0;
    *(int4*)&Ks[0][srow * LDT + sseg * 16 + 8] = kr1;
    union { int4 v; ushort u[8]; } r0, r1;
    r0.v = vr0; r1.v = vr1;
    #pragma unroll
    for (int j = 0; j < 8; ++j) {
      uint pk = (uint)r0.u[j] | ((uint)r1.u[j] << 16);
      *(uint*)&Vt[0][(vs * 8 + j) * LDT + vpos] = pk;
    }
  }

  for (int c = 0; c < SEQ / 64; ++c) {
    const int buf = c & 1;
    __syncthreads();   // tile c's LDS writes visible (also covers Q staging)

    // ---- issue next tile's global loads ----
    if (c + 1 < SEQ / 64) {
      const ushort* kp = kbase + (size_t)(c + 1) * tstep;
      const ushort* vv = vbase + (size_t)(c + 1) * tstep;
      kr0 = *(const int4*)(kp + 0);
      kr1 = *(const int4*)(kp + 8);
      vr0 = *(const int4*)(vv);
      vr1 = *(const int4*)(vv + 3 * DIM);
    }

    // ---- S^T = K Q^T ----
    f32x4 st[4][4];
    #pragma unroll
    for (int qt = 0; qt < 4; ++qt)
      #pragma unroll
      for (int kt = 0; kt < 4; ++kt) st[qt][kt] = (f32x4){0, 0, 0, 0};
    __builtin_amdgcn_s_setprio(1);
    #pragma unroll
    for (int kk = 0; kk < 2; ++kk) {
      half8 kfr[4], qfr[4];
      #pragma unroll
      for (int kt = 0; kt < 4; ++kt)
        kfr[kt] = *(const half8*)&Ks[buf][(kt * 16 + l16) * LDT + kk * 32 + quad * 8];
      #pragma unroll
      for (int qt = 0; qt < 4; ++qt)
        qfr[qt] = *(const half8*)&Qs[(w * 64 + qt * 16 + l16) * LDT + kk * 32 + quad * 8];
      #pragma unroll
      for (int qt = 0; qt < 4; ++qt)
        #pragma unroll
        for (int kt = 0; kt < 4; ++kt)
          st[qt][kt] = __builtin_amdgcn_mfma_f32_16x16x32_f16(kfr[kt], qfr[qt], st[qt][kt], 0, 0, 0);
    }
    __builtin_amdgcn_s_setprio(0);

    // ---- P^T = exp2(S^T) in-register -> B-frags (scale pre-folded in Q) ----
    union { half8 h; uint u[4]; } pf[4][2];
    #pragma unroll
    for (int qt = 0; qt < 4; ++qt) {
      float p[4][4];
      #pragma unroll
      for (int kt = 0; kt < 4; ++kt)
        #pragma unroll
        for (int i = 0; i < 4; ++i) {
          p[kt][i] = __builtin_amdgcn_exp2f(st[qt][kt][i]);
          lacc[qt] += p[kt][i];
        }
      #pragma unroll
      for (int kc = 0; kc < 2; ++kc) {
        union { fp16x2 h; uint u; } c01, c23, c45, c67;
        c01.h = __builtin_amdgcn_cvt_pkrtz(p[2 * kc][0], p[2 * kc][1]);
        c23.h = __builtin_amdgcn_cvt_pkrtz(p[2 * kc][2], p[2 * kc][3]);
        c45.h = __builtin_amdgcn_cvt_pkrtz(p[2 * kc + 1][0], p[2 * kc + 1][1]);
        c67.h = __builtin_amdgcn_cvt_pkrtz(p[2 * kc + 1][2], p[2 * kc + 1][3]);
        pf[qt][kc].u[0] = c01.u; pf[qt][kc].u[1] = c23.u;
        pf[qt][kc].u[2] = c45.u; pf[qt][kc].u[3] = c67.u;
      }
    }

    // ---- O^T += V^T P^T ----
    __builtin_amdgcn_s_setprio(1);
    #pragma unroll
    for (int kc = 0; kc < 2; ++kc) {
      half8 vfr[4];
      #pragma unroll
      for (int nt = 0; nt < 4; ++nt)
        vfr[nt] = *(const half8*)&Vt[buf][(nt * 16 + l16) * LDT + kc * 32 + quad * 8];
      #pragma unroll
      for (int qt = 0; qt < 4; ++qt)
        #pragma unroll
        for (int nt = 0; nt < 4; ++nt)
          ot[qt][nt] = __builtin_amdgcn_mfma_f32_16x16x32_f16(vfr[nt], pf[qt][kc].h, ot[qt][nt], 0, 0, 0);
    }
    __builtin_amdgcn_s_setprio(0);

    // ---- write prefetched tile c+1 into the other buffer ----
    if (c + 1 < SEQ / 64) {
      const int nb = buf ^ 1;
      *(int4*)&Ks[nb][srow * LDT + sseg * 16 + 0] = kr0;
      *(int4*)&Ks[nb][srow * LDT + sseg * 16 + 8] = kr1;
      union { int4 v; ushort u[8]; } r0, r1;
      r0.v = vr0; r1.v = vr1;
      #pragma unroll
      for (int j = 0; j < 8; ++j) {
        uint pk = (uint)r0.u[j] | ((uint)r1.u[j] << 16);
        *(uint*)&Vt[nb][(vs * 8 + j) * LDT + vpos] = pk;
      }
    }
  }

  // ---- finalize ----
  __syncthreads();
  #pragma unroll
  for (int qt = 0; qt < 4; ++qt) {
    float lsum = lacc[qt];
    lsum += __shfl_xor(lsum, 16);
    lsum += __shfl_xor(lsum, 32);
    float inv = 1.0f / lsum;
    #pragma unroll
    for (int nt = 0; nt < 4; ++nt)
      #pragma unroll
      for (int i = 0; i < 4; ++i)
        Qs[(w * 64 + qt * 16 + l16) * LDT + nt * 16 + quad * 4 + i] =
            f2h(ot[qt][nt][i] * inv);
  }
  __syncthreads();
  #pragma unroll
  for (int pass = 0; pass < 2; ++pass) {
    const int orow = pass * 128 + (t >> 1), oseg = t & 1;
    size_t gbase = (size_t)(b * SEQ + q0 + orow) * DIM + h * HD + oseg * 32;
    #pragma unroll
    for (int e = 0; e < 4; ++e)
      *(int4*)&attn_out[gbase + e * 8] = *(const int4*)&Qs[orow * LDT + oseg * 32 + e * 8];
  }
}

extern "C" void kernel_launch(void* const* d_in, const int* in_sizes, int n_in,
                              void* d_out, int out_size, void* d_ws, size_t ws_size,
                              hipStream_t stream) {
  const float* x      = (const float*)d_in[0];
  const float* w_qkv  = (const float*)d_in[1];
  const float* w_proj = (const float*)d_in[2];
  const float* b_proj = (const float*)d_in[3];

  char* ws = (char*)d_ws;
  ushort* x_h   = (ushort*)(ws + 0);          // 16,777,216 B
  ushort* wq_h  = (ushort*)(ws + 16777216);   //  6,291,456 B
  ushort* wp_h  = (ushort*)(ws + 23068672);   //  2,097,152 B
  ushort* qkv_h = (ushort*)(ws + 25165824);   // 50,331,648 B
  ushort* at_h  = (ushort*)(ws + 75497472);   // 16,777,216 B (total ~92.3 MB)

  cvt3_f32_to_f16<<<12288, 256, 0, stream>>>(
      (const float4*)x, (const float4*)w_qkv, (const float4*)w_proj,
      (ushort4*)x_h, (ushort4*)wq_h, (ushort4*)wp_h);

  // qkv = x @ w_qkv^T : [8192,1024] x [3072,1024]^T -> f16 [8192,3072]
  gemm_bt256<<<64 * 12, 256, 0, stream>>>(x_h, wq_h, qkv_h, 8192, 3072, 1024);
  // attention -> f16 [8192,1024]  (1D grid: id%8 constant per (h,b) -> XCD)
  attn_mfma<<<512, 256, 0, stream>>>(qkv_h, at_h);
  // out = attn @ w_proj^T + b : fp32 [8192,1024]
  // 64x128 tiles: 128 x 8 = 1024 blocks = 4/CU (TLP fix)
  gemm_bt128<<<1024, 256, 0, stream>>>(at_h, wp_h, (float*)d_out,
                                       b_proj, 8192, 1024, 1024);
}

// Round 11
// 254.995 us; speedup vs baseline: 1.0523x; 1.0523x over previous
//
#include <hip/hip_runtime.h>
#include <cstdint>

#define DIM   1024
#define NH    16
#define HD    64
#define SEQ   2048
#define BATCH 4
// 0.125 * log2(e): fold qk scale into exp2 (applied to Q in gemm_bt256 epilogue)
#define QK_EXP2_SCALE 0.18033688011112042f

typedef _Float16 half8  __attribute__((ext_vector_type(8)));
typedef __fp16   fp16x2 __attribute__((ext_vector_type(2)));
typedef float    f32x4  __attribute__((ext_vector_type(4)));

#define GLOBAL_AS __attribute__((address_space(1)))
#define LDS_AS    __attribute__((address_space(3)))

__device__ __forceinline__ ushort f2h(float f) {
  union { _Float16 h; ushort u; } c; c.h = (_Float16)f; return c.u;  // RNE
}
// async global->LDS, 16B/lane; LDS dest is wave-uniform base + lane*16
__device__ __forceinline__ void async_cp16(const ushort* g, ushort* l) {
  __builtin_amdgcn_global_load_lds((const GLOBAL_AS uint32_t*)g,
                                   (LDS_AS uint32_t*)l, 16, 0, 0);
}

// fused f32->f16 convert of x, w_qkv, w_proj
__global__ __launch_bounds__(256) void cvt3_f32_to_f16(
    const float4* __restrict__ x, const float4* __restrict__ wq,
    const float4* __restrict__ wp, ushort4* __restrict__ xo,
    ushort4* __restrict__ wqo, ushort4* __restrict__ wpo) {
  int i = blockIdx.x * 256 + threadIdx.x;
  const float4* src; ushort4* dst; int j;
  if (i < 2097152)      { src = x;  dst = xo;  j = i; }
  else if (i < 2883584) { src = wq; dst = wqo; j = i - 2097152; }
  else                  { src = wp; dst = wpo; j = i - 2883584; }
  float4 v = src[j];
  dst[j] = make_ushort4(f2h(v.x), f2h(v.y), f2h(v.z), f2h(v.w));
}

// C = A(MxK) * Bt(NxK)^T, f16 in, fp32 accum. 128x256 tile, BK=64 --
// MEASURED BEST of the 4-wave family. R7's 128x384 regressed (86us):
// 320 regs/wave -> 1 block/CU (unified-file rule: arch+AGPR <= 256/wave
// for 2 blocks/CU). acc[4][8]=128 AGPR fits. (256,3) collapses (R2).
// T2 LDS swizzle (verified R3: conflicts 1.4e7 -> ~0, -12us).
// Epilogue: Q cols (<DIM) pre-scaled by QK_EXP2_SCALE for attn exp2.
// FROZEN since R8.
__global__ __launch_bounds__(256, 2) void gemm_bt256(
    const ushort* __restrict__ A, const ushort* __restrict__ Bt,
    ushort* __restrict__ Ch, int M, int N, int K) {
  __shared__ ushort As[128 * 64];
  __shared__ ushort Bs[256 * 64];
  const int t    = threadIdx.x;
  const int w    = t >> 6;
  const int lane = t & 63;
  const int quad = lane >> 4;
  const int l16  = lane & 15;
  const int wm   = w >> 1, wn = w & 1;

  // supertile swizzle (8 m-blocks x full n-strip)
  const int num_n = N >> 8;
  const int SUPER = 8;
  const int bid   = blockIdx.x;
  const int strip = bid / (SUPER * num_n);
  const int rem   = bid % (SUPER * num_n);
  const int m0 = (strip * SUPER + (rem % SUPER)) * 128;
  const int n0 = (rem / SUPER) * 256;

  f32x4 acc[4][8];
  #pragma unroll
  for (int it = 0; it < 4; ++it)
    #pragma unroll
    for (int jt = 0; jt < 8; ++jt) acc[it][jt] = (f32x4){0, 0, 0, 0};

  const int srow = lane >> 3;                          // 0..7 within 8-row group
  const int scol = ((lane & 7) ^ (lane >> 3)) * 8;     // swizzled source chunk
  const int cxa  = l16 & 7;                            // read-side row&7

  for (int k0 = 0; k0 < K; k0 += 64) {
    __syncthreads();   // prev-tile frag reads done
    #pragma unroll
    for (int p = 0; p < 4; ++p) {    // A: wave w stages rows w*32..w*32+31
      const int rbase = w * 32 + p * 8;
      async_cp16(&A[(size_t)(m0 + rbase + srow) * K + k0 + scol], &As[rbase * 64]);
    }
    #pragma unroll
    for (int p = 0; p < 8; ++p) {    // B: wave w stages rows w*64..w*64+63
      const int rbase = w * 64 + p * 8;
      async_cp16(&Bt[(size_t)(n0 + rbase + srow) * K + k0 + scol], &Bs[rbase * 64]);
    }
    __syncthreads();   // staging drained
    #pragma unroll
    for (int kk = 0; kk < 2; ++kk) {
      const int ko = ((kk * 4 + quad) ^ cxa) * 8;   // swizzled read chunk
      half8 a[4];
      #pragma unroll
      for (int it = 0; it < 4; ++it)
        a[it] = *(const half8*)&As[(wm * 64 + it * 16 + l16) * 64 + ko];
      #pragma unroll
      for (int jt = 0; jt < 8; ++jt) {
        half8 b = *(const half8*)&Bs[(wn * 128 + jt * 16 + l16) * 64 + ko];
        #pragma unroll
        for (int it = 0; it < 4; ++it)
          acc[it][jt] = __builtin_amdgcn_mfma_f32_16x16x32_f16(a[it], b, acc[it][jt], 0, 0, 0);
      }
    }
  }

  #pragma unroll
  for (int it = 0; it < 4; ++it)
    #pragma unroll
    for (int jt = 0; jt < 8; ++jt) {
      const int colbase = n0 + wn * 128 + jt * 16;
      const float qs = (colbase < DIM) ? QK_EXP2_SCALE : 1.0f;
      #pragma unroll
      for (int i = 0; i < 4; ++i) {
        int row = m0 + wm * 64 + it * 16 + quad * 4 + i;   // C/D row=quad*4+reg
        int col = n0 + wn * 128 + jt * 16 + l16;           // C/D col=lane&15
        Ch[(size_t)row * N + col] = f2h(acc[it][jt][i] * qs);
      }
    }
}

// 128x128-tile proj GEMM -- REVERTED to R8-exact (plain bounds, 512
// blocks): best measured total (254.8us). Three configs tested: plain
// (R8, best), (256,2) (R9, +6us), 64x128@(256,3) 1024 blocks (R10, +13us).
// The compiler balances this one fine on its own; the ledger's "~100us
// bt128" was substantially graph/launch gaps, not this kernel. FROZEN.
__global__ __launch_bounds__(256) void gemm_bt128(
    const ushort* __restrict__ A, const ushort* __restrict__ Bt,
    float* __restrict__ Cf, const float* __restrict__ bias,
    int M, int N, int K) {
  __shared__ ushort As[128 * 64];
  __shared__ ushort Bs[128 * 64];
  const int t    = threadIdx.x;
  const int w    = t >> 6;
  const int lane = t & 63;
  const int quad = lane >> 4;
  const int l16  = lane & 15;
  const int wm   = w >> 1, wn = w & 1;

  const int num_n = N >> 7;
  const int SUPER = 8;
  const int bid   = blockIdx.x;
  const int strip = bid / (SUPER * num_n);
  const int rem   = bid % (SUPER * num_n);
  const int m0 = (strip * SUPER + (rem % SUPER)) * 128;
  const int n0 = (rem / SUPER) * 128;

  f32x4 acc[4][4];
  #pragma unroll
  for (int it = 0; it < 4; ++it)
    #pragma unroll
    for (int jt = 0; jt < 4; ++jt) acc[it][jt] = (f32x4){0, 0, 0, 0};

  const int srow = lane >> 3;
  const int scol = ((lane & 7) ^ (lane >> 3)) * 8;
  const int cxa  = l16 & 7;

  for (int k0 = 0; k0 < K; k0 += 64) {
    __syncthreads();
    #pragma unroll
    for (int p = 0; p < 4; ++p) {
      const int rbase = w * 32 + p * 8;
      async_cp16(&A[(size_t)(m0 + rbase + srow) * K + k0 + scol], &As[rbase * 64]);
      async_cp16(&Bt[(size_t)(n0 + rbase + srow) * K + k0 + scol], &Bs[rbase * 64]);
    }
    __syncthreads();
    #pragma unroll
    for (int kk = 0; kk < 2; ++kk) {
      const int ko = ((kk * 4 + quad) ^ cxa) * 8;
      half8 a[4], b[4];
      #pragma unroll
      for (int it = 0; it < 4; ++it)
        a[it] = *(const half8*)&As[(wm * 64 + it * 16 + l16) * 64 + ko];
      #pragma unroll
      for (int jt = 0; jt < 4; ++jt)
        b[jt] = *(const half8*)&Bs[(wn * 64 + jt * 16 + l16) * 64 + ko];
      #pragma unroll
      for (int it = 0; it < 4; ++it)
        #pragma unroll
        for (int jt = 0; jt < 4; ++jt)
          acc[it][jt] = __builtin_amdgcn_mfma_f32_16x16x32_f16(a[it], b[jt], acc[it][jt], 0, 0, 0);
    }
  }

  #pragma unroll
  for (int it = 0; it < 4; ++it)
    #pragma unroll
    for (int jt = 0; jt < 4; ++jt)
      #pragma unroll
      for (int i = 0; i < 4; ++i) {
        int row = m0 + wm * 64 + it * 16 + quad * 4 + i;
        int col = n0 + wn * 64 + jt * 16 + l16;
        Cf[(size_t)row * N + col] = acc[it][jt][i] + bias[col];
      }
}

// MFMA flash attention -- v2 body + XCD co-location (R8: 84.5us, FETCH
// 25.4MB) + R11: DENOMINATOR VIA MFMA. Old path: lacc[qt] += p (64 VALU
// adds/tile/wave, ~128 cyc) + final __shfl_xor reduce. New: one extra PV
// MFMA per (qt,kc) with A = all-ones: D[r][q] = sum_k P^T[k][q] -- every
// row r holds the denominator of q=col. C/D col=lane&15 == this lane's q
// in the ot store, so no cross-lane reduce at all. Cost +8 MFMA/tile
// (~38 cyc) + 16 AGPR (total ~192/wave < 256 budget, 2 blocks/CU kept);
// saves ~128 VALU cyc/tile (VALUBusy 39 > MfmaUtil 33 -> VALU is the more
// contended pipe). Denominator now sums the same f16-rounded P as the
// numerator (self-consistent).
// Transposed-S (S^T = K Q^T; P^T in registers as PV B-operand; V^T staged
// with verified key permutation). NO-max softmax. 64 q/wave, 256 q/block;
// 64-key tiles, K/V double-buffered, 1 barrier/tile. QK scale pre-folded
// into Q by gemm_bt256, so P = exp2(st) directly.
__global__ __launch_bounds__(256, 2) void attn_mfma(
    const ushort* __restrict__ qkv, ushort* __restrict__ attn_out) {
  constexpr int LDT = 68;
  __shared__ ushort Qs[256 * LDT];
  __shared__ ushort Ks[2][64 * LDT];
  __shared__ ushort Vt[2][64 * LDT];   // [d][permuted key]

  const int t    = threadIdx.x;
  const int w    = t >> 6;
  const int lane = t & 63;
  const int quad = lane >> 4;
  const int l16  = lane & 15;

  // XCD co-location: blocks of one (h,b) have ids {hb + 64*qc} == hb (mod 8)
  const int id = blockIdx.x;
  const int hb = id & 63;
  const int q0 = (id >> 6) * 256;
  const int h  = hb & 15;
  const int b  = hb >> 4;

  const int srow = t >> 2;   // K staging row 0..63
  const int sseg = t & 3;    // 16-elem segment
  const int vp   = t & 31;   // V key-pair index m: keys (2m, 2m+1)
  const int vs   = t >> 5;   // V d-segment of 8
  const int vpos = ((vp >> 4) << 5) + (((vp >> 1) & 3) << 3)
                 + (((vp >> 3) & 1) << 2) + ((vp & 1) << 1);

  // ---- stage Q: 256 rows x 64 d (2 passes) ----
  #pragma unroll
  for (int pass = 0; pass < 2; ++pass) {
    const int qrow = pass * 128 + (t >> 1), qseg = t & 1;
    const ushort* qp = qkv + (size_t)(b * SEQ + q0 + qrow) * (3 * DIM)
                       + h * HD + qseg * 32;
    #pragma unroll
    for (int e = 0; e < 4; ++e)
      *(int4*)&Qs[qrow * LDT + qseg * 32 + e * 8] = *(const int4*)(qp + e * 8);
  }

  f32x4 ot[4][4];   // O^T: ot[qt][nt][i] = O[q=w*64+qt*16+l16][d=nt*16+quad*4+i]
  f32x4 dacc[4];    // denominator acc: dacc[qt][i] = sum_k P[k][q=qt*16+l16]
  #pragma unroll
  for (int qt = 0; qt < 4; ++qt) {
    dacc[qt] = (f32x4){0, 0, 0, 0};
    #pragma unroll
    for (int nt = 0; nt < 4; ++nt) ot[qt][nt] = (f32x4){0, 0, 0, 0};
  }

  // all-ones A-fragment for the denominator MFMA
  half8 vone;
  #pragma unroll
  for (int i = 0; i < 8; ++i) vone[i] = (_Float16)1.0f;

  // per-thread K/V tile base pointers (tile step = 64 rows of qkv)
  const ushort* kbase = qkv + (size_t)(b * SEQ + srow) * (3 * DIM)
                        + DIM + h * HD + sseg * 16;
  const ushort* vbase = qkv + (size_t)(b * SEQ + 2 * vp) * (3 * DIM)
                        + 2 * DIM + h * HD + vs * 8;
  const size_t tstep = (size_t)64 * (3 * DIM);

  // ---- prefetch + stage tile 0 ----
  int4 kr0 = *(const int4*)(kbase + 0);
  int4 kr1 = *(const int4*)(kbase + 8);
  int4 vr0 = *(const int4*)(vbase);
  int4 vr1 = *(const int4*)(vbase + 3 * DIM);
  {
    *(int4*)&Ks[0][srow * LDT + sseg * 16 + 0] = kr0;
    *(int4*)&Ks[0][srow * LDT + sseg * 16 + 8] = kr1;
    union { int4 v; ushort u[8]; } r0, r1;
    r0.v = vr0; r1.v = vr1;
    #pragma unroll
    for (int j = 0; j < 8; ++j) {
      uint pk = (uint)r0.u[j] | ((uint)r1.u[j] << 16);
      *(uint*)&Vt[0][(vs * 8 + j) * LDT + vpos] = pk;
    }
  }

  for (int c = 0; c < SEQ / 64; ++c) {
    const int buf = c & 1;
    __syncthreads();   // tile c's LDS writes visible (also covers Q staging)

    // ---- issue next tile's global loads ----
    if (c + 1 < SEQ / 64) {
      const ushort* kp = kbase + (size_t)(c + 1) * tstep;
      const ushort* vv = vbase + (size_t)(c + 1) * tstep;
      kr0 = *(const int4*)(kp + 0);
      kr1 = *(const int4*)(kp + 8);
      vr0 = *(const int4*)(vv);
      vr1 = *(const int4*)(vv + 3 * DIM);
    }

    // ---- S^T = K Q^T ----
    f32x4 st[4][4];
    #pragma unroll
    for (int qt = 0; qt < 4; ++qt)
      #pragma unroll
      for (int kt = 0; kt < 4; ++kt) st[qt][kt] = (f32x4){0, 0, 0, 0};
    __builtin_amdgcn_s_setprio(1);
    #pragma unroll
    for (int kk = 0; kk < 2; ++kk) {
      half8 kfr[4], qfr[4];
      #pragma unroll
      for (int kt = 0; kt < 4; ++kt)
        kfr[kt] = *(const half8*)&Ks[buf][(kt * 16 + l16) * LDT + kk * 32 + quad * 8];
      #pragma unroll
      for (int qt = 0; qt < 4; ++qt)
        qfr[qt] = *(const half8*)&Qs[(w * 64 + qt * 16 + l16) * LDT + kk * 32 + quad * 8];
      #pragma unroll
      for (int qt = 0; qt < 4; ++qt)
        #pragma unroll
        for (int kt = 0; kt < 4; ++kt)
          st[qt][kt] = __builtin_amdgcn_mfma_f32_16x16x32_f16(kfr[kt], qfr[qt], st[qt][kt], 0, 0, 0);
    }
    __builtin_amdgcn_s_setprio(0);

    // ---- P^T = exp2(S^T) in-register -> B-frags (scale pre-folded in Q) ----
    union { half8 h; uint u[4]; } pf[4][2];
    #pragma unroll
    for (int qt = 0; qt < 4; ++qt) {
      float p[4][4];
      #pragma unroll
      for (int kt = 0; kt < 4; ++kt)
        #pragma unroll
        for (int i = 0; i < 4; ++i)
          p[kt][i] = __builtin_amdgcn_exp2f(st[qt][kt][i]);
      #pragma unroll
      for (int kc = 0; kc < 2; ++kc) {
        union { fp16x2 h; uint u; } c01, c23, c45, c67;
        c01.h = __builtin_amdgcn_cvt_pkrtz(p[2 * kc][0], p[2 * kc][1]);
        c23.h = __builtin_amdgcn_cvt_pkrtz(p[2 * kc][2], p[2 * kc][3]);
        c45.h = __builtin_amdgcn_cvt_pkrtz(p[2 * kc + 1][0], p[2 * kc + 1][1]);
        c67.h = __builtin_amdgcn_cvt_pkrtz(p[2 * kc + 1][2], p[2 * kc + 1][3]);
        pf[qt][kc].u[0] = c01.u; pf[qt][kc].u[1] = c23.u;
        pf[qt][kc].u[2] = c45.u; pf[qt][kc].u[3] = c67.u;
      }
    }

    // ---- O^T += V^T P^T ; den += 1^T P^T ----
    __builtin_amdgcn_s_setprio(1);
    #pragma unroll
    for (int kc = 0; kc < 2; ++kc) {
      half8 vfr[4];
      #pragma unroll
      for (int nt = 0; nt < 4; ++nt)
        vfr[nt] = *(const half8*)&Vt[buf][(nt * 16 + l16) * LDT + kc * 32 + quad * 8];
      #pragma unroll
      for (int qt = 0; qt < 4; ++qt) {
        #pragma unroll
        for (int nt = 0; nt < 4; ++nt)
          ot[qt][nt] = __builtin_amdgcn_mfma_f32_16x16x32_f16(vfr[nt], pf[qt][kc].h, ot[qt][nt], 0, 0, 0);
        dacc[qt] = __builtin_amdgcn_mfma_f32_16x16x32_f16(vone, pf[qt][kc].h, dacc[qt], 0, 0, 0);
      }
    }
    __builtin_amdgcn_s_setprio(0);

    // ---- write prefetched tile c+1 into the other buffer ----
    if (c + 1 < SEQ / 64) {
      const int nb = buf ^ 1;
      *(int4*)&Ks[nb][srow * LDT + sseg * 16 + 0] = kr0;
      *(int4*)&Ks[nb][srow * LDT + sseg * 16 + 8] = kr1;
      union { int4 v; ushort u[8]; } r0, r1;
      r0.v = vr0; r1.v = vr1;
      #pragma unroll
      for (int j = 0; j < 8; ++j) {
        uint pk = (uint)r0.u[j] | ((uint)r1.u[j] << 16);
        *(uint*)&Vt[nb][(vs * 8 + j) * LDT + vpos] = pk;
      }
    }
  }

  // ---- finalize: dacc[qt] already holds this lane's q denominator ----
  __syncthreads();
  #pragma unroll
  for (int qt = 0; qt < 4; ++qt) {
    float inv = 1.0f / dacc[qt][0];
    #pragma unroll
    for (int nt = 0; nt < 4; ++nt)
      #pragma unroll
      for (int i = 0; i < 4; ++i)
        Qs[(w * 64 + qt * 16 + l16) * LDT + nt * 16 + quad * 4 + i] =
            f2h(ot[qt][nt][i] * inv);
  }
  __syncthreads();
  #pragma unroll
  for (int pass = 0; pass < 2; ++pass) {
    const int orow = pass * 128 + (t >> 1), oseg = t & 1;
    size_t gbase = (size_t)(b * SEQ + q0 + orow) * DIM + h * HD + oseg * 32;
    #pragma unroll
    for (int e = 0; e < 4; ++e)
      *(int4*)&attn_out[gbase + e * 8] = *(const int4*)&Qs[orow * LDT + oseg * 32 + e * 8];
  }
}

extern "C" void kernel_launch(void* const* d_in, const int* in_sizes, int n_in,
                              void* d_out, int out_size, void* d_ws, size_t ws_size,
                              hipStream_t stream) {
  const float* x      = (const float*)d_in[0];
  const float* w_qkv  = (const float*)d_in[1];
  const float* w_proj = (const float*)d_in[2];
  const float* b_proj = (const float*)d_in[3];

  char* ws = (char*)d_ws;
  ushort* x_h   = (ushort*)(ws + 0);          // 16,777,216 B
  ushort* wq_h  = (ushort*)(ws + 16777216);   //  6,291,456 B
  ushort* wp_h  = (ushort*)(ws + 23068672);   //  2,097,152 B
  ushort* qkv_h = (ushort*)(ws + 25165824);   // 50,331,648 B
  ushort* at_h  = (ushort*)(ws + 75497472);   // 16,777,216 B (total ~92.3 MB)

  cvt3_f32_to_f16<<<12288, 256, 0, stream>>>(
      (const float4*)x, (const float4*)w_qkv, (const float4*)w_proj,
      (ushort4*)x_h, (ushort4*)wq_h, (ushort4*)wp_h);

  // qkv = x @ w_qkv^T : [8192,1024] x [3072,1024]^T -> f16 [8192,3072]
  gemm_bt256<<<64 * 12, 256, 0, stream>>>(x_h, wq_h, qkv_h, 8192, 3072, 1024);
  // attention -> f16 [8192,1024]  (1D grid: id%8 constant per (h,b) -> XCD)
  attn_mfma<<<512, 256, 0, stream>>>(qkv_h, at_h);
  // out = attn @ w_proj^T + b : fp32 [8192,1024]
  gemm_bt128<<<64 * 8, 256, 0, stream>>>(at_h, wp_h, (float*)d_out,
                                         b_proj, 8192, 1024, 1024);
}

// Round 12
// 248.286 us; speedup vs baseline: 1.0807x; 1.0270x over previous
//
#include <hip/hip_runtime.h>
#include <cstdint>

#define DIM   1024
#define NH    16
#define HD    64
#define SEQ   2048
#define BATCH 4
// 0.125 * log2(e): fold qk scale into exp2 (applied to Q in gemm_bt256 epilogue)
#define QK_EXP2_SCALE 0.18033688011112042f

typedef _Float16 half8  __attribute__((ext_vector_type(8)));
typedef __fp16   fp16x2 __attribute__((ext_vector_type(2)));
typedef float    f32x4  __attribute__((ext_vector_type(4)));

#define GLOBAL_AS __attribute__((address_space(1)))
#define LDS_AS    __attribute__((address_space(3)))

__device__ __forceinline__ ushort f2h(float f) {
  union { _Float16 h; ushort u; } c; c.h = (_Float16)f; return c.u;  // RNE
}
// async global->LDS, 16B/lane; LDS dest is wave-uniform base + lane*16
__device__ __forceinline__ void async_cp16(const ushort* g, ushort* l) {
  __builtin_amdgcn_global_load_lds((const GLOBAL_AS uint32_t*)g,
                                   (LDS_AS uint32_t*)l, 16, 0, 0);
}

// fused f32->f16 convert of x, w_qkv, w_proj
__global__ __launch_bounds__(256) void cvt3_f32_to_f16(
    const float4* __restrict__ x, const float4* __restrict__ wq,
    const float4* __restrict__ wp, ushort4* __restrict__ xo,
    ushort4* __restrict__ wqo, ushort4* __restrict__ wpo) {
  int i = blockIdx.x * 256 + threadIdx.x;
  const float4* src; ushort4* dst; int j;
  if (i < 2097152)      { src = x;  dst = xo;  j = i; }
  else if (i < 2883584) { src = wq; dst = wqo; j = i - 2097152; }
  else                  { src = wp; dst = wpo; j = i - 2883584; }
  float4 v = src[j];
  dst[j] = make_ushort4(f2h(v.x), f2h(v.y), f2h(v.z), f2h(v.w));
}

// C = A(MxK) * Bt(NxK)^T, f16 in, fp32 accum. 128x256 tile, BK=64 --
// MEASURED BEST of the 4-wave family. R7's 128x384 regressed (86us):
// 320 regs/wave -> 1 block/CU (unified-file rule: arch+AGPR <= 256/wave
// for 2 blocks/CU). acc[4][8]=128 AGPR fits. (256,3) collapses (R2).
// T2 LDS swizzle (verified R3: conflicts 1.4e7 -> ~0, -12us).
// Epilogue: Q cols (<DIM) pre-scaled by QK_EXP2_SCALE for attn exp2.
// FROZEN since R8.
__global__ __launch_bounds__(256, 2) void gemm_bt256(
    const ushort* __restrict__ A, const ushort* __restrict__ Bt,
    ushort* __restrict__ Ch, int M, int N, int K) {
  __shared__ ushort As[128 * 64];
  __shared__ ushort Bs[256 * 64];
  const int t    = threadIdx.x;
  const int w    = t >> 6;
  const int lane = t & 63;
  const int quad = lane >> 4;
  const int l16  = lane & 15;
  const int wm   = w >> 1, wn = w & 1;

  // supertile swizzle (8 m-blocks x full n-strip)
  const int num_n = N >> 8;
  const int SUPER = 8;
  const int bid   = blockIdx.x;
  const int strip = bid / (SUPER * num_n);
  const int rem   = bid % (SUPER * num_n);
  const int m0 = (strip * SUPER + (rem % SUPER)) * 128;
  const int n0 = (rem / SUPER) * 256;

  f32x4 acc[4][8];
  #pragma unroll
  for (int it = 0; it < 4; ++it)
    #pragma unroll
    for (int jt = 0; jt < 8; ++jt) acc[it][jt] = (f32x4){0, 0, 0, 0};

  const int srow = lane >> 3;                          // 0..7 within 8-row group
  const int scol = ((lane & 7) ^ (lane >> 3)) * 8;     // swizzled source chunk
  const int cxa  = l16 & 7;                            // read-side row&7

  for (int k0 = 0; k0 < K; k0 += 64) {
    __syncthreads();   // prev-tile frag reads done
    #pragma unroll
    for (int p = 0; p < 4; ++p) {    // A: wave w stages rows w*32..w*32+31
      const int rbase = w * 32 + p * 8;
      async_cp16(&A[(size_t)(m0 + rbase + srow) * K + k0 + scol], &As[rbase * 64]);
    }
    #pragma unroll
    for (int p = 0; p < 8; ++p) {    // B: wave w stages rows w*64..w*64+63
      const int rbase = w * 64 + p * 8;
      async_cp16(&Bt[(size_t)(n0 + rbase + srow) * K + k0 + scol], &Bs[rbase * 64]);
    }
    __syncthreads();   // staging drained
    #pragma unroll
    for (int kk = 0; kk < 2; ++kk) {
      const int ko = ((kk * 4 + quad) ^ cxa) * 8;   // swizzled read chunk
      half8 a[4];
      #pragma unroll
      for (int it = 0; it < 4; ++it)
        a[it] = *(const half8*)&As[(wm * 64 + it * 16 + l16) * 64 + ko];
      #pragma unroll
      for (int jt = 0; jt < 8; ++jt) {
        half8 b = *(const half8*)&Bs[(wn * 128 + jt * 16 + l16) * 64 + ko];
        #pragma unroll
        for (int it = 0; it < 4; ++it)
          acc[it][jt] = __builtin_amdgcn_mfma_f32_16x16x32_f16(a[it], b, acc[it][jt], 0, 0, 0);
      }
    }
  }

  #pragma unroll
  for (int it = 0; it < 4; ++it)
    #pragma unroll
    for (int jt = 0; jt < 8; ++jt) {
      const int colbase = n0 + wn * 128 + jt * 16;
      const float qs = (colbase < DIM) ? QK_EXP2_SCALE : 1.0f;
      #pragma unroll
      for (int i = 0; i < 4; ++i) {
        int row = m0 + wm * 64 + it * 16 + quad * 4 + i;   // C/D row=quad*4+reg
        int col = n0 + wn * 128 + jt * 16 + l16;           // C/D col=lane&15
        Ch[(size_t)row * N + col] = f2h(acc[it][jt][i] * qs);
      }
    }
}

// 128x128-tile proj GEMM -- R8-exact (plain bounds, 512 blocks): best
// measured total. Three configs tested: plain (R8, best), (256,2)
// (R9, +6us), 64x128@(256,3) 1024 blocks (R10, +13us). FROZEN.
__global__ __launch_bounds__(256) void gemm_bt128(
    const ushort* __restrict__ A, const ushort* __restrict__ Bt,
    float* __restrict__ Cf, const float* __restrict__ bias,
    int M, int N, int K) {
  __shared__ ushort As[128 * 64];
  __shared__ ushort Bs[128 * 64];
  const int t    = threadIdx.x;
  const int w    = t >> 6;
  const int lane = t & 63;
  const int quad = lane >> 4;
  const int l16  = lane & 15;
  const int wm   = w >> 1, wn = w & 1;

  const int num_n = N >> 7;
  const int SUPER = 8;
  const int bid   = blockIdx.x;
  const int strip = bid / (SUPER * num_n);
  const int rem   = bid % (SUPER * num_n);
  const int m0 = (strip * SUPER + (rem % SUPER)) * 128;
  const int n0 = (rem / SUPER) * 128;

  f32x4 acc[4][4];
  #pragma unroll
  for (int it = 0; it < 4; ++it)
    #pragma unroll
    for (int jt = 0; jt < 4; ++jt) acc[it][jt] = (f32x4){0, 0, 0, 0};

  const int srow = lane >> 3;
  const int scol = ((lane & 7) ^ (lane >> 3)) * 8;
  const int cxa  = l16 & 7;

  for (int k0 = 0; k0 < K; k0 += 64) {
    __syncthreads();
    #pragma unroll
    for (int p = 0; p < 4; ++p) {
      const int rbase = w * 32 + p * 8;
      async_cp16(&A[(size_t)(m0 + rbase + srow) * K + k0 + scol], &As[rbase * 64]);
      async_cp16(&Bt[(size_t)(n0 + rbase + srow) * K + k0 + scol], &Bs[rbase * 64]);
    }
    __syncthreads();
    #pragma unroll
    for (int kk = 0; kk < 2; ++kk) {
      const int ko = ((kk * 4 + quad) ^ cxa) * 8;
      half8 a[4], b[4];
      #pragma unroll
      for (int it = 0; it < 4; ++it)
        a[it] = *(const half8*)&As[(wm * 64 + it * 16 + l16) * 64 + ko];
      #pragma unroll
      for (int jt = 0; jt < 4; ++jt)
        b[jt] = *(const half8*)&Bs[(wn * 64 + jt * 16 + l16) * 64 + ko];
      #pragma unroll
      for (int it = 0; it < 4; ++it)
        #pragma unroll
        for (int jt = 0; jt < 4; ++jt)
          acc[it][jt] = __builtin_amdgcn_mfma_f32_16x16x32_f16(a[it], b[jt], acc[it][jt], 0, 0, 0);
    }
  }

  #pragma unroll
  for (int it = 0; it < 4; ++it)
    #pragma unroll
    for (int jt = 0; jt < 4; ++jt)
      #pragma unroll
      for (int i = 0; i < 4; ++i) {
        int row = m0 + wm * 64 + it * 16 + quad * 4 + i;
        int col = n0 + wn * 64 + jt * 16 + l16;
        Cf[(size_t)row * N + col] = acc[it][jt][i] + bias[col];
      }
}

// MFMA flash attention -- v2 body + XCD co-location (R8) + MFMA
// denominator (R11: 81.3us, MfmaUtil 40) + R12: Q IN REGISTERS.
// Q is loop-invariant but was re-read from LDS every tile (8 of 24
// ds_read_b128/tile/wave). qreg[4][2] (16 VGPR, mapping verified correct
// by R6's passing run) removes those reads AND the Q staging pass.
// CRITICAL: the Qs LDS array stays DECLARED (finalize O-staging uses it)
// so LDS_Block_Size stays 69632 -> the allocator's LDS-derived occupancy
// target stays 2 waves/EU -> 256-reg budget (removing it shrinks LDS and
// triggers the R5 spill trap). Ledger: ~128 arch + 80 AGPR = 208 <= 256,
// 2 blocks/CU preserved.
// Transposed-S (S^T = K Q^T; P^T in registers as PV B-operand; V^T staged
// with verified key permutation). NO-max softmax; denominator via
// all-ones-A MFMA (D[r][q]=sum_k P^T[k][q], col=l16 == own q, no
// cross-lane reduce). 64 q/wave, 256 q/block; 64-key tiles, K/V
// double-buffered, 1 barrier/tile. QK scale pre-folded into Q.
__global__ __launch_bounds__(256, 2) void attn_mfma(
    const ushort* __restrict__ qkv, ushort* __restrict__ attn_out) {
  constexpr int LDT = 68;
  __shared__ ushort Qs[256 * LDT];     // dead until finalize (O staging)
  __shared__ ushort Ks[2][64 * LDT];
  __shared__ ushort Vt[2][64 * LDT];   // [d][permuted key]

  const int t    = threadIdx.x;
  const int w    = t >> 6;
  const int lane = t & 63;
  const int quad = lane >> 4;
  const int l16  = lane & 15;

  // XCD co-location: blocks of one (h,b) have ids {hb + 64*qc} == hb (mod 8)
  const int id = blockIdx.x;
  const int hb = id & 63;
  const int q0 = (id >> 6) * 256;
  const int h  = hb & 15;
  const int b  = hb >> 4;

  const int srow = t >> 2;   // K staging row 0..63
  const int sseg = t & 3;    // 16-elem segment
  const int vp   = t & 31;   // V key-pair index m: keys (2m, 2m+1)
  const int vs   = t >> 5;   // V d-segment of 8
  const int vpos = ((vp >> 4) << 5) + (((vp >> 1) & 3) << 3)
                 + (((vp >> 3) & 1) << 2) + ((vp & 1) << 1);

  // ---- Q -> registers (loop-invariant; replaces Qs staging + per-tile
  // qfr ds_reads; mapping == old Qs[(w*64+qt*16+l16)*LDT + kk*32+quad*8]) ----
  half8 qreg[4][2];
  #pragma unroll
  for (int qt = 0; qt < 4; ++qt)
    #pragma unroll
    for (int kk = 0; kk < 2; ++kk)
      qreg[qt][kk] = *(const half8*)(qkv
          + (size_t)(b * SEQ + q0 + w * 64 + qt * 16 + l16) * (3 * DIM)
          + h * HD + kk * 32 + quad * 8);

  f32x4 ot[4][4];   // O^T: ot[qt][nt][i] = O[q=w*64+qt*16+l16][d=nt*16+quad*4+i]
  f32x4 dacc[4];    // denominator acc: dacc[qt][i] = sum_k P[k][q=qt*16+l16]
  #pragma unroll
  for (int qt = 0; qt < 4; ++qt) {
    dacc[qt] = (f32x4){0, 0, 0, 0};
    #pragma unroll
    for (int nt = 0; nt < 4; ++nt) ot[qt][nt] = (f32x4){0, 0, 0, 0};
  }

  // all-ones A-fragment for the denominator MFMA
  half8 vone;
  #pragma unroll
  for (int i = 0; i < 8; ++i) vone[i] = (_Float16)1.0f;

  // per-thread K/V tile base pointers (tile step = 64 rows of qkv)
  const ushort* kbase = qkv + (size_t)(b * SEQ + srow) * (3 * DIM)
                        + DIM + h * HD + sseg * 16;
  const ushort* vbase = qkv + (size_t)(b * SEQ + 2 * vp) * (3 * DIM)
                        + 2 * DIM + h * HD + vs * 8;
  const size_t tstep = (size_t)64 * (3 * DIM);

  // ---- prefetch + stage tile 0 ----
  int4 kr0 = *(const int4*)(kbase + 0);
  int4 kr1 = *(const int4*)(kbase + 8);
  int4 vr0 = *(const int4*)(vbase);
  int4 vr1 = *(const int4*)(vbase + 3 * DIM);
  {
    *(int4*)&Ks[0][srow * LDT + sseg * 16 + 0] = kr0;
    *(int4*)&Ks[0][srow * LDT + sseg * 16 + 8] = kr1;
    union { int4 v; ushort u[8]; } r0, r1;
    r0.v = vr0; r1.v = vr1;
    #pragma unroll
    for (int j = 0; j < 8; ++j) {
      uint pk = (uint)r0.u[j] | ((uint)r1.u[j] << 16);
      *(uint*)&Vt[0][(vs * 8 + j) * LDT + vpos] = pk;
    }
  }

  for (int c = 0; c < SEQ / 64; ++c) {
    const int buf = c & 1;
    __syncthreads();   // tile c's LDS writes visible

    // ---- issue next tile's global loads ----
    if (c + 1 < SEQ / 64) {
      const ushort* kp = kbase + (size_t)(c + 1) * tstep;
      const ushort* vv = vbase + (size_t)(c + 1) * tstep;
      kr0 = *(const int4*)(kp + 0);
      kr1 = *(const int4*)(kp + 8);
      vr0 = *(const int4*)(vv);
      vr1 = *(const int4*)(vv + 3 * DIM);
    }

    // ---- S^T = K Q^T ----
    f32x4 st[4][4];
    #pragma unroll
    for (int qt = 0; qt < 4; ++qt)
      #pragma unroll
      for (int kt = 0; kt < 4; ++kt) st[qt][kt] = (f32x4){0, 0, 0, 0};
    __builtin_amdgcn_s_setprio(1);
    #pragma unroll
    for (int kk = 0; kk < 2; ++kk) {
      half8 kfr[4];
      #pragma unroll
      for (int kt = 0; kt < 4; ++kt)
        kfr[kt] = *(const half8*)&Ks[buf][(kt * 16 + l16) * LDT + kk * 32 + quad * 8];
      #pragma unroll
      for (int qt = 0; qt < 4; ++qt)
        #pragma unroll
        for (int kt = 0; kt < 4; ++kt)
          st[qt][kt] = __builtin_amdgcn_mfma_f32_16x16x32_f16(kfr[kt], qreg[qt][kk], st[qt][kt], 0, 0, 0);
    }
    __builtin_amdgcn_s_setprio(0);

    // ---- P^T = exp2(S^T) in-register -> B-frags (scale pre-folded in Q) ----
    union { half8 h; uint u[4]; } pf[4][2];
    #pragma unroll
    for (int qt = 0; qt < 4; ++qt) {
      float p[4][4];
      #pragma unroll
      for (int kt = 0; kt < 4; ++kt)
        #pragma unroll
        for (int i = 0; i < 4; ++i)
          p[kt][i] = __builtin_amdgcn_exp2f(st[qt][kt][i]);
      #pragma unroll
      for (int kc = 0; kc < 2; ++kc) {
        union { fp16x2 h; uint u; } c01, c23, c45, c67;
        c01.h = __builtin_amdgcn_cvt_pkrtz(p[2 * kc][0], p[2 * kc][1]);
        c23.h = __builtin_amdgcn_cvt_pkrtz(p[2 * kc][2], p[2 * kc][3]);
        c45.h = __builtin_amdgcn_cvt_pkrtz(p[2 * kc + 1][0], p[2 * kc + 1][1]);
        c67.h = __builtin_amdgcn_cvt_pkrtz(p[2 * kc + 1][2], p[2 * kc + 1][3]);
        pf[qt][kc].u[0] = c01.u; pf[qt][kc].u[1] = c23.u;
        pf[qt][kc].u[2] = c45.u; pf[qt][kc].u[3] = c67.u;
      }
    }

    // ---- O^T += V^T P^T ; den += 1^T P^T ----
    __builtin_amdgcn_s_setprio(1);
    #pragma unroll
    for (int kc = 0; kc < 2; ++kc) {
      half8 vfr[4];
      #pragma unroll
      for (int nt = 0; nt < 4; ++nt)
        vfr[nt] = *(const half8*)&Vt[buf][(nt * 16 + l16) * LDT + kc * 32 + quad * 8];
      #pragma unroll
      for (int qt = 0; qt < 4; ++qt) {
        #pragma unroll
        for (int nt = 0; nt < 4; ++nt)
          ot[qt][nt] = __builtin_amdgcn_mfma_f32_16x16x32_f16(vfr[nt], pf[qt][kc].h, ot[qt][nt], 0, 0, 0);
        dacc[qt] = __builtin_amdgcn_mfma_f32_16x16x32_f16(vone, pf[qt][kc].h, dacc[qt], 0, 0, 0);
      }
    }
    __builtin_amdgcn_s_setprio(0);

    // ---- write prefetched tile c+1 into the other buffer ----
    if (c + 1 < SEQ / 64) {
      const int nb = buf ^ 1;
      *(int4*)&Ks[nb][srow * LDT + sseg * 16 + 0] = kr0;
      *(int4*)&Ks[nb][srow * LDT + sseg * 16 + 8] = kr1;
      union { int4 v; ushort u[8]; } r0, r1;
      r0.v = vr0; r1.v = vr1;
      #pragma unroll
      for (int j = 0; j < 8; ++j) {
        uint pk = (uint)r0.u[j] | ((uint)r1.u[j] << 16);
        *(uint*)&Vt[nb][(vs * 8 + j) * LDT + vpos] = pk;
      }
    }
  }

  // ---- finalize: dacc[qt] holds this lane's q denominator; O via Qs ----
  __syncthreads();
  #pragma unroll
  for (int qt = 0; qt < 4; ++qt) {
    float inv = 1.0f / dacc[qt][0];
    #pragma unroll
    for (int nt = 0; nt < 4; ++nt)
      #pragma unroll
      for (int i = 0; i < 4; ++i)
        Qs[(w * 64 + qt * 16 + l16) * LDT + nt * 16 + quad * 4 + i] =
            f2h(ot[qt][nt][i] * inv);
  }
  __syncthreads();
  #pragma unroll
  for (int pass = 0; pass < 2; ++pass) {
    const int orow = pass * 128 + (t >> 1), oseg = t & 1;
    size_t gbase = (size_t)(b * SEQ + q0 + orow) * DIM + h * HD + oseg * 32;
    #pragma unroll
    for (int e = 0; e < 4; ++e)
      *(int4*)&attn_out[gbase + e * 8] = *(const int4*)&Qs[orow * LDT + oseg * 32 + e * 8];
  }
}

extern "C" void kernel_launch(void* const* d_in, const int* in_sizes, int n_in,
                              void* d_out, int out_size, void* d_ws, size_t ws_size,
                              hipStream_t stream) {
  const float* x      = (const float*)d_in[0];
  const float* w_qkv  = (const float*)d_in[1];
  const float* w_proj = (const float*)d_in[2];
  const float* b_proj = (const float*)d_in[3];

  char* ws = (char*)d_ws;
  ushort* x_h   = (ushort*)(ws + 0);          // 16,777,216 B
  ushort* wq_h  = (ushort*)(ws + 16777216);   //  6,291,456 B
  ushort* wp_h  = (ushort*)(ws + 23068672);   //  2,097,152 B
  ushort* qkv_h = (ushort*)(ws + 25165824);   // 50,331,648 B
  ushort* at_h  = (ushort*)(ws + 75497472);   // 16,777,216 B (total ~92.3 MB)

  cvt3_f32_to_f16<<<12288, 256, 0, stream>>>(
      (const float4*)x, (const float4*)w_qkv, (const float4*)w_proj,
      (ushort4*)x_h, (ushort4*)wq_h, (ushort4*)wp_h);

  // qkv = x @ w_qkv^T : [8192,1024] x [3072,1024]^T -> f16 [8192,3072]
  gemm_bt256<<<64 * 12, 256, 0, stream>>>(x_h, wq_h, qkv_h, 8192, 3072, 1024);
  // attention -> f16 [8192,1024]  (1D grid: id%8 constant per (h,b) -> XCD)
  attn_mfma<<<512, 256, 0, stream>>>(qkv_h, at_h);
  // out = attn @ w_proj^T + b : fp32 [8192,1024]
  gemm_bt128<<<64 * 8, 256, 0, stream>>>(at_h, wp_h, (float*)d_out,
                                         b_proj, 8192, 1024, 1024);
}